// Round 1
// baseline (322.098 us; speedup 1.0000x reference)
//
#include <hip/hip_runtime.h>
#include <hip/hip_bf16.h>

// Mlp_moe: patch MLP (12608x768 -> 3072 -> 768, gelu-exact) + 6-class 2-route MoE on cls tokens.
// Strategy: bf16 MFMA GEMMs (m97 structure: 128x128 tile, BK=64, global_load_lds w=16,
// slot-XOR LDS swizzle both-sides), fp64-accurate gate for the discrete routing decision.

typedef __bf16 bf16x8 __attribute__((ext_vector_type(8)));
typedef float f32x4 __attribute__((ext_vector_type(4)));
typedef unsigned short u16;

#define DEVINL __device__ __forceinline__

DEVINL u16 f2bf(float f) {
  unsigned int u = __builtin_bit_cast(unsigned int, f);
  u += 0x7FFFu + ((u >> 16) & 1u);
  return (u16)(u >> 16);
}

DEVINL float gelu_exact(float v) {
  return 0.5f * v * (1.0f + erff(v * 0.70710678118654752440f));
}

DEVINL void async_load16(const void* g, void* l) {
  __builtin_amdgcn_global_load_lds(
      (const __attribute__((address_space(1))) unsigned int*)g,
      (__attribute__((address_space(3))) unsigned int*)l, 16, 0, 0);
}

// ---------------- conversion kernels ----------------
__global__ void cvt_bf16(const float* __restrict__ in, u16* __restrict__ out, int n) {
  const int i = (blockIdx.x * 256 + threadIdx.x) * 4;
  if (i >= n) return;
  const float4 v = *(const float4*)(in + i);
  ushort4 u;
  u.x = f2bf(v.x); u.y = f2bf(v.y); u.z = f2bf(v.z); u.w = f2bf(v.w);
  *(ushort4*)(out + i) = u;
}

// split x (64,203,768) into cls (64*6,768) and patch (64*197,768), bf16
__global__ void cvt_x(const float* __restrict__ x, u16* __restrict__ xc, u16* __restrict__ xp) {
  const int e = (blockIdx.x * 256 + threadIdx.x) * 4;  // < 64*203*768, grid exact
  const int t = e / 768, d = e % 768;
  const int b = t / 203, i = t % 203;
  const float4 v = *(const float4*)(x + e);
  ushort4 u;
  u.x = f2bf(v.x); u.y = f2bf(v.y); u.z = f2bf(v.z); u.w = f2bf(v.w);
  if (i < 6) *(ushort4*)(xc + (size_t)(b * 6 + i) * 768 + d) = u;
  else       *(ushort4*)(xp + (size_t)(b * 197 + (i - 6)) * 768 + d) = u;
}

// ---------------- gate / routing decision (exact-ish, fp64 accum) ----------------
__global__ void gate_kernel(const float* __restrict__ x,
                            const float* __restrict__ gate_pair,
                            const float* __restrict__ balance_bias,
                            int* __restrict__ rstar, float* __restrict__ wstar) {
  const int lane = threadIdx.x & 63, wid = threadIdx.x >> 6;
  const int idx = blockIdx.x * 4 + wid;  // 0..383  (b*6+n)
  const int b = idx / 6, n = idx % 6;
  const float* xv = x + (size_t)(b * 203 + n) * 768;
  const float* w0 = gate_pair + (size_t)(n * 2 + 0) * 768;
  const float* w1 = gate_pair + (size_t)(n * 2 + 1) * 768;
  double xx = 0, a00 = 0, a11 = 0, d0 = 0, d1 = 0;
  for (int d = lane; d < 768; d += 64) {
    double xd = xv[d], g0 = w0[d], g1 = w1[d];
    xx += xd * xd; a00 += g0 * g0; a11 += g1 * g1; d0 += xd * g0; d1 += xd * g1;
  }
#pragma unroll
  for (int off = 32; off; off >>= 1) {
    xx  += __shfl_xor(xx, off);
    a00 += __shfl_xor(a00, off);
    a11 += __shfl_xor(a11, off);
    d0  += __shfl_xor(d0, off);
    d1  += __shfl_xor(d1, off);
  }
  if (lane == 0) {
    double nx = fmax(sqrt(xx), 1e-12), n0 = fmax(sqrt(a00), 1e-12), n1 = fmax(sqrt(a11), 1e-12);
    double l0 = d0 / (nx * n0) + (double)balance_bias[n * 2 + 0];
    double l1 = d1 / (nx * n1) + (double)balance_bias[n * 2 + 1];
    const int r = (l1 > l0) ? 1 : 0;  // jnp.argmax: first max wins on tie
    double m = fmax(l0, l1);
    double e0 = exp(l0 - m), e1 = exp(l1 - m);
    rstar[idx] = r;
    wstar[idx] = (float)(((r == 1) ? e1 : e0) / (e0 + e1));
  }
}

// ---------------- main GEMM: C = A(MxK) * B(NxK)^T + bias, m97 structure ----------------
// EPI 0: gelu -> bf16 out (ldc given).  EPI 1: f32 scatter into d_out patch rows (ldc=768).
template <int EPI>
__global__ __launch_bounds__(256, 2) void gemm_bt(
    const u16* __restrict__ A, const u16* __restrict__ B,
    const float* __restrict__ bias, void* __restrict__ Cout,
    int M, int K, int ldc) {
  __shared__ u16 As[128 * 64];
  __shared__ u16 Bs[128 * 64];
  const int lane = threadIdx.x & 63;
  const int wid  = threadIdx.x >> 6;
  const int wr   = wid >> 1, wc = wid & 1;
  const int tm   = blockIdx.y * 128;
  const int tn   = blockIdx.x * 128;

  f32x4 acc[4][4] = {};
  const int rA = lane >> 3;  // row within 8-row chunk
  const int sA = lane & 7;   // 16B slot within 128B row

  const int ksteps = K >> 6;
  for (int ks = 0; ks < ksteps; ++ks) {
    const int k0 = ks << 6;
#pragma unroll
    for (int c = 0; c < 4; ++c) {
      const int chunk = wid * 4 + c;     // 0..15
      const int row   = chunk * 8 + rA;  // 0..127
      int grow = tm + row;
      grow = grow < M ? grow : (M - 1);  // clamp: garbage rows never stored
      const int slot = sA ^ (row & 7);   // inverse-swizzled SOURCE (linear LDS dest)
      async_load16(A + (size_t)grow * K + k0 + slot * 8, (char*)As + chunk * 1024);
    }
#pragma unroll
    for (int c = 0; c < 4; ++c) {
      const int chunk = wid * 4 + c;
      const int row   = chunk * 8 + rA;
      const int slot  = sA ^ (row & 7);
      async_load16(B + (size_t)(tn + row) * K + k0 + slot * 8, (char*)Bs + chunk * 1024);
    }
    __syncthreads();  // compiler drains vmcnt before s_barrier
#pragma unroll
    for (int kk = 0; kk < 2; ++kk) {
      bf16x8 af[4], bfv[4];
#pragma unroll
      for (int im = 0; im < 4; ++im) {
        const int R = wr * 64 + im * 16 + (lane & 15);
        const int s = (kk * 4 + (lane >> 4)) ^ (R & 7);
        af[im] = *(const bf16x8*)((const char*)As + R * 128 + s * 16);
      }
#pragma unroll
      for (int in_ = 0; in_ < 4; ++in_) {
        const int R = wc * 64 + in_ * 16 + (lane & 15);
        const int s = (kk * 4 + (lane >> 4)) ^ (R & 7);
        bfv[in_] = *(const bf16x8*)((const char*)Bs + R * 128 + s * 16);
      }
#pragma unroll
      for (int im = 0; im < 4; ++im)
#pragma unroll
        for (int in_ = 0; in_ < 4; ++in_)
          acc[im][in_] = __builtin_amdgcn_mfma_f32_16x16x32_bf16(
              af[im], bfv[in_], acc[im][in_], 0, 0, 0);
    }
    __syncthreads();
  }

  const int cn  = lane & 15;
  const int cr4 = (lane >> 4) * 4;
#pragma unroll
  for (int im = 0; im < 4; ++im) {
#pragma unroll
    for (int in_ = 0; in_ < 4; ++in_) {
      const int col = tn + wc * 64 + in_ * 16 + cn;
      const float bv = bias[col];
#pragma unroll
      for (int j = 0; j < 4; ++j) {
        const int row = tm + wr * 64 + im * 16 + cr4 + j;
        if (row < M) {
          const float v = acc[im][in_][j] + bv;
          if (EPI == 0) {
            ((u16*)Cout)[(size_t)row * ldc + col] = f2bf(gelu_exact(v));
          } else {
            const int b = row / 197, p = row % 197;
            ((float*)Cout)[((size_t)(b * 203 + 6 + p)) * 768 + col] = v;
          }
        }
      }
    }
  }
}

// ---------------- candidate GEMM: per (n,r) 64x768 = hid_slice(64x3072) @ Wout^T ----------------
__global__ __launch_bounds__(256, 2) void cand_gemm(
    const u16* __restrict__ hid, const u16* __restrict__ wao,
    const float* __restrict__ bout, const int* __restrict__ rstar,
    const float* __restrict__ wstar, float* __restrict__ out) {
  __shared__ u16 As[64 * 64];
  __shared__ u16 Bs[128 * 64];
  const int g = blockIdx.y, n = g >> 1, r = g & 1;
  // TASK_PAIRS atoms: src[n] = {n/2, 3+(n&1)} (L,R); dst[n][r] = src[n][1-r]
  const int src_a = (r == 0) ? (n >> 1) : (3 + (n & 1));
  const int dst_a = (r == 1) ? (n >> 1) : (3 + (n & 1));
  const int tn = blockIdx.x * 128;
  const int lane = threadIdx.x & 63, wid = threadIdx.x >> 6;
  const int rA = lane >> 3, sA = lane & 7;
  const u16* Bbase = wao + (size_t)dst_a * 768 * 3072;
  f32x4 acc[4][2] = {};
  for (int ks = 0; ks < 48; ++ks) {
    const int k0 = ks << 6;
#pragma unroll
    for (int c = 0; c < 2; ++c) {
      const int chunk = wid * 2 + c;    // 0..7
      const int row   = chunk * 8 + rA; // b in 0..63
      const int slot  = sA ^ (row & 7);
      async_load16(hid + (size_t)(row * 6 + n) * 15360 + src_a * 3072 + k0 + slot * 8,
                   (char*)As + chunk * 1024);
    }
#pragma unroll
    for (int c = 0; c < 4; ++c) {
      const int chunk = wid * 4 + c;
      const int row   = chunk * 8 + rA;
      const int slot  = sA ^ (row & 7);
      async_load16(Bbase + (size_t)(tn + row) * 3072 + k0 + slot * 8,
                   (char*)Bs + chunk * 1024);
    }
    __syncthreads();
#pragma unroll
    for (int kk = 0; kk < 2; ++kk) {
      bf16x8 af[4], bfv[2];
#pragma unroll
      for (int im = 0; im < 4; ++im) {
        const int R = im * 16 + (lane & 15);
        const int s = (kk * 4 + (lane >> 4)) ^ (R & 7);
        af[im] = *(const bf16x8*)((const char*)As + R * 128 + s * 16);
      }
#pragma unroll
      for (int in_ = 0; in_ < 2; ++in_) {
        const int R = wid * 32 + in_ * 16 + (lane & 15);
        const int s = (kk * 4 + (lane >> 4)) ^ (R & 7);
        bfv[in_] = *(const bf16x8*)((const char*)Bs + R * 128 + s * 16);
      }
#pragma unroll
      for (int im = 0; im < 4; ++im)
#pragma unroll
        for (int in_ = 0; in_ < 2; ++in_)
          acc[im][in_] = __builtin_amdgcn_mfma_f32_16x16x32_bf16(
              af[im], bfv[in_], acc[im][in_], 0, 0, 0);
    }
    __syncthreads();
  }
  const int cn = lane & 15, cr4 = (lane >> 4) * 4;
#pragma unroll
  for (int im = 0; im < 4; ++im)
#pragma unroll
    for (int in_ = 0; in_ < 2; ++in_) {
      const int col = tn + wid * 32 + in_ * 16 + cn;
      const float bv = bout[dst_a * 768 + col];
#pragma unroll
      for (int j = 0; j < 4; ++j) {
        const int b = im * 16 + cr4 + j;  // 0..63
        const int idx = b * 6 + n;
        if (rstar[idx] == r)
          out[((size_t)(b * 203 + n)) * 768 + col] = (acc[im][in_][j] + bv) * wstar[idx];
      }
    }
}

// ---------------- launch ----------------
extern "C" void kernel_launch(void* const* d_in, const int* in_sizes, int n_in,
                              void* d_out, int out_size, void* d_ws, size_t ws_size,
                              hipStream_t stream) {
  const float* x     = (const float*)d_in[0];
  const float* fc1w  = (const float*)d_in[1];
  const float* fc1b  = (const float*)d_in[2];
  const float* fc2w  = (const float*)d_in[3];
  const float* fc2b  = (const float*)d_in[4];
  const float* gpair = (const float*)d_in[5];
  const float* aiw   = (const float*)d_in[6];
  const float* aib   = (const float*)d_in[7];
  const float* aow   = (const float*)d_in[8];
  const float* aob   = (const float*)d_in[9];
  const float* bbias = (const float*)d_in[10];
  float* out = (float*)d_out;

  char* ws = (char*)d_ws;
  u16* xp   = (u16*)(ws + 0);          // 12608x768 bf16
  u16* xc   = (u16*)(ws + 19365888);   // 384x768
  u16* w1   = (u16*)(ws + 19955712);   // 3072x768
  u16* w2   = (u16*)(ws + 24674304);   // 768x3072
  u16* wai  = (u16*)(ws + 29392896);   // 5x3072x768
  u16* wao  = (u16*)(ws + 52985856);   // 5x768x3072
  u16* hb   = (u16*)(ws + 76578816);   // 12608x3072
  u16* hid  = (u16*)(ws + 154042368);  // 384x15360
  int*   rstar = (int*)(ws + 165838848);
  float* wstar = (float*)(ws + 165840384);
  if (ws_size < 165841920) return;  // need ~158 MiB scratch

  cvt_x<<<9744, 256, 0, stream>>>(x, xc, xp);
  cvt_bf16<<<2304, 256, 0, stream>>>(fc1w, w1, 2359296);
  cvt_bf16<<<2304, 256, 0, stream>>>(fc2w, w2, 2359296);
  cvt_bf16<<<11520, 256, 0, stream>>>(aiw, wai, 11796480);
  cvt_bf16<<<11520, 256, 0, stream>>>(aow, wao, 11796480);
  gate_kernel<<<96, 256, 0, stream>>>(x, gpair, bbias, rstar, wstar);
  // patch fc1 + gelu -> h (bf16)
  gemm_bt<0><<<dim3(24, 99), 256, 0, stream>>>(xp, w1, fc1b, hb, 12608, 768, 3072);
  // hid_all = gelu(cls @ atom_in_w^T + b) for all 5 atoms (bias is (5,3072) contiguous)
  gemm_bt<0><<<dim3(120, 3), 256, 0, stream>>>(xc, wai, aib, hid, 384, 768, 15360);
  // patch fc2 -> d_out (scattered to b*203+6+p rows)
  gemm_bt<1><<<dim3(6, 99), 256, 0, stream>>>(hb, w2, fc2b, out, 12608, 3072, 768);
  // route candidates, chosen one written * prob
  cand_gemm<<<dim3(6, 12), 256, 0, stream>>>(hid, wao, aob, rstar, wstar, out);
}